// Round 5
// baseline (729.499 us; speedup 1.0000x reference)
//
#include <hip/hip_runtime.h>
#include <hip/hip_bf16.h>

#define BATCH 32
#define WW 900
#define CCH 256
#define PVAL 450
#define KHALF 128     // K columns per block (K-split x2)
#define MSTRIP 128    // M rows per block
#define NCHUNK 64     // B rows staged per chunk
#define NCHUNKS 15    // 15*64 = 960 >= 900

typedef __bf16 bf16x8 __attribute__((ext_vector_type(8)));
typedef float f32x4 __attribute__((ext_vector_type(4)));

// ---------------- norm pass 1: partial sums of squares ----------------
__global__ void nc_norm_partial(const float* __restrict__ x1,
                                const float* __restrict__ x2,
                                float* __restrict__ sums) {
    int blk = blockIdx.x;
    int seg = blk & 3;
    int b = (blk >> 2) & 31;
    int which = blk >> 7;
    const float* x = which ? x2 : x1;
    int c = threadIdx.x;
    const float* p = x + ((size_t)b * WW + seg * 225) * CCH + c;
    float s = 0.f;
    #pragma unroll 8
    for (int w = 0; w < 225; ++w) {
        float v = p[(size_t)w * CCH];
        s = fmaf(v, v, s);
    }
    sums[(((which << 5) | b) * 4 + seg) * CCH + c] = s;
}

// ---------------- norm pass 2 ----------------
__global__ void nc_norm_finalize(float* __restrict__ ws) {
    int i = blockIdx.x * 256 + threadIdx.x;
    int c = i & 255;
    int wb = i >> 8;
    const float* s = ws + (size_t)wb * 4 * CCH + c;
    float t = (s[0] + s[CCH]) + (s[2 * CCH] + s[3 * CCH]);
    ws[65536 + i] = rsqrtf(fmaxf(t, 1e-12f));
}

// ---------------- main GEMM + diagonal reduce, template-ablated ----------------
// MODE 0: full (writes out).  MODE 1: no epilogue (acc->sink).
// MODE 2: no staging after chunk 0.  MODE 3: no ds_read/MFMA (acc from st regs).
// MODE!=0 write only to dbg = ws sums region (recomputed each launch; replay-safe).
template <int MODE>
__global__ __launch_bounds__(256, 2)
void nc_corr_t(const float* __restrict__ x1,
               const float* __restrict__ x2,
               const float* __restrict__ ws,
               float* __restrict__ out,
               float* __restrict__ dbg) {
    __shared__ __bf16 Abuf[MSTRIP * KHALF];      // 32 KB
    __shared__ __bf16 Bbuf[2][NCHUNK * KHALF];   // 2 x 16 KB
    __shared__ float partial[WW];                // 3.6 KB

    const int tid = threadIdx.x;
    const int b = blockIdx.x & 31;
    const int strip = (blockIdx.x >> 5) & 7;
    const int kh = blockIdx.x >> 8;
    const int m0 = strip * MSTRIP;
    const int k0 = kh * KHALF;

    const float* __restrict__ inv1 = ws + 65536 + b * CCH + k0;
    const float* __restrict__ inv2 = ws + 65536 + (BATCH + b) * CCH + k0;
    const float* __restrict__ x1b = x1 + (size_t)b * WW * CCH + k0;
    const float* __restrict__ x2b = x2 + (size_t)b * WW * CCH + k0;

    for (int i = tid; i < WW; i += 256) partial[i] = 0.f;

    const int lane = tid & 63;
    const int wave = tid >> 6;
    const int fr = lane & 15;
    const int fq = lane >> 4;

    // ---- Stage A once ----
    {
        const int arow = tid >> 1;
        const int gb = (tid & 1) * 8;
        const int grow = m0 + arow;
        const float* src = x1b + (size_t)grow * CCH;
        #pragma unroll
        for (int u = 0; u < 8; ++u) {
            const int g = gb + u;
            bf16x8 v;
            if (grow < WW) {
                float4 f0 = *(const float4*)(src + g * 8);
                float4 f1 = *(const float4*)(src + g * 8 + 4);
                float4 i0 = *(const float4*)(inv1 + g * 8);
                float4 i1 = *(const float4*)(inv1 + g * 8 + 4);
                v[0] = (__bf16)(f0.x * i0.x); v[1] = (__bf16)(f0.y * i0.y);
                v[2] = (__bf16)(f0.z * i0.z); v[3] = (__bf16)(f0.w * i0.w);
                v[4] = (__bf16)(f1.x * i1.x); v[5] = (__bf16)(f1.y * i1.y);
                v[6] = (__bf16)(f1.z * i1.z); v[7] = (__bf16)(f1.w * i1.w);
            } else {
                #pragma unroll
                for (int e = 0; e < 8; ++e) v[e] = (__bf16)0.f;
            }
            *(bf16x8*)(&Abuf[arow * KHALF + ((g ^ (arow & 7)) << 3)]) = v;
        }
    }

    // ---- B staging ----
    const int srow = tid >> 2;
    const int scg = tid & 3;
    float4 iv[8];
    #pragma unroll
    for (int q = 0; q < 8; ++q) iv[q] = *(const float4*)(inv2 + scg * 32 + q * 4);

    float4 st[8];

    auto loadB = [&](int chunk) {
        const int row = chunk * NCHUNK + srow;
        if (row < WW) {
            const float* s = x2b + (size_t)row * CCH + scg * 32;
            #pragma unroll
            for (int q = 0; q < 8; ++q) st[q] = *(const float4*)(s + q * 4);
        } else {
            #pragma unroll
            for (int q = 0; q < 8; ++q) st[q] = make_float4(0.f, 0.f, 0.f, 0.f);
        }
    };
    auto writeB = [&](int buf) {
        #pragma unroll
        for (int u = 0; u < 4; ++u) {
            bf16x8 v;
            float4 a = st[2 * u], bb = st[2 * u + 1];
            float4 ia = iv[2 * u], ib = iv[2 * u + 1];
            v[0] = (__bf16)(a.x * ia.x);  v[1] = (__bf16)(a.y * ia.y);
            v[2] = (__bf16)(a.z * ia.z);  v[3] = (__bf16)(a.w * ia.w);
            v[4] = (__bf16)(bb.x * ib.x); v[5] = (__bf16)(bb.y * ib.y);
            v[6] = (__bf16)(bb.z * ib.z); v[7] = (__bf16)(bb.w * ib.w);
            const int g = (scg * 4 + u) ^ (srow & 7);
            *(bf16x8*)(&Bbuf[buf][srow * KHALF + g * 8]) = v;
        }
    };

    loadB(0);
    writeB(0);
    __syncthreads();

    float sink = 0.f;
    int cur = 0;
    for (int chunk = 0; chunk < NCHUNKS; ++chunk) {
        if (MODE != 2 && chunk + 1 < NCHUNKS) loadB(chunk + 1);

        f32x4 acc[2][4];
        #pragma unroll
        for (int mt = 0; mt < 2; ++mt)
            #pragma unroll
            for (int nt = 0; nt < 4; ++nt)
                acc[mt][nt] = (f32x4){0.f, 0.f, 0.f, 0.f};

        if (MODE != 3) {
            #pragma unroll
            for (int kk = 0; kk < 4; ++kk) {
                bf16x8 af[2], bfr[4];
                #pragma unroll
                for (int mt = 0; mt < 2; ++mt) {
                    const int row = wave * 32 + mt * 16 + fr;
                    const int g = (kk * 4 + fq) ^ (row & 7);
                    af[mt] = *(const bf16x8*)(&Abuf[row * KHALF + g * 8]);
                }
                #pragma unroll
                for (int nt = 0; nt < 4; ++nt) {
                    const int row = nt * 16 + fr;
                    const int g = (kk * 4 + fq) ^ (row & 7);
                    bfr[nt] = *(const bf16x8*)(&Bbuf[cur][row * KHALF + g * 8]);
                }
                #pragma unroll
                for (int mt = 0; mt < 2; ++mt)
                    #pragma unroll
                    for (int nt = 0; nt < 4; ++nt)
                        acc[mt][nt] = __builtin_amdgcn_mfma_f32_16x16x32_bf16(
                            af[mt], bfr[nt], acc[mt][nt], 0, 0, 0);
            }
        } else {
            // keep epilogue inputs live without MFMA: derive acc from staged regs
            #pragma unroll
            for (int mt = 0; mt < 2; ++mt)
                #pragma unroll
                for (int nt = 0; nt < 4; ++nt) {
                    float4 s = st[(mt * 4 + nt) & 7];
                    acc[mt][nt] = (f32x4){s.x, s.y, s.z, s.w};
                }
        }

        if (MODE != 1) {
            const int base_mi = (m0 + wave * 32) - (chunk * NCHUNK) + 4 * fq - fr - PVAL + 1800;
            #pragma unroll
            for (int d = -3; d <= 1; ++d) {
                f32x4 comb = (f32x4){0.f, 0.f, 0.f, 0.f};
                #pragma unroll
                for (int mt = 0; mt < 2; ++mt) {
                    const int nt = mt - d;
                    if (nt >= 0 && nt < 4) comb += acc[mt][nt];
                }
                int j0 = base_mi + 16 * d;
                if (j0 >= 1800) j0 -= 900;
                if (j0 >= 900) j0 -= 900;
                #pragma unroll
                for (int r = 0; r < 4; ++r) {
                    int j = j0 + r;
                    if (j >= WW) j -= WW;
                    unsafeAtomicAdd(&partial[j], comb[r]);
                }
            }
        } else {
            // keep acc live each chunk (prevents MFMA DCE), epilogue removed
            #pragma unroll
            for (int mt = 0; mt < 2; ++mt)
                #pragma unroll
                for (int nt = 0; nt < 4; ++nt)
                    sink += acc[mt][nt][0] + acc[mt][nt][1] + acc[mt][nt][2] + acc[mt][nt][3];
        }

        if (MODE != 2 && chunk + 1 < NCHUNKS) writeB(cur ^ 1);
        __syncthreads();
        cur ^= 1;
    }

    if (MODE == 0) {
        for (int i = tid; i < WW; i += 256)
            unsafeAtomicAdd(&out[(size_t)b * WW + i], partial[i]);
    } else if (MODE == 1) {
        dbg[(blockIdx.x & 255) * 256 + tid] = sink;
    } else {
        for (int i = tid; i < WW; i += 256)
            dbg[(size_t)(blockIdx.x & 63) * WW + i] = partial[i];
    }
}

extern "C" void kernel_launch(void* const* d_in, const int* in_sizes, int n_in,
                              void* d_out, int out_size, void* d_ws, size_t ws_size,
                              hipStream_t stream) {
    const float* x1 = (const float*)d_in[0];
    const float* x2 = (const float*)d_in[1];
    float* out = (float*)d_out;
    float* ws = (float*)d_ws;   // 320 KB used: sums [0,64K) floats, inv [64K,80K) floats
    float* dbg = ws;            // ablation sink = sums region (recomputed each launch)

    hipMemsetAsync(d_out, 0, (size_t)out_size * sizeof(float), stream);
    nc_norm_partial<<<256, 256, 0, stream>>>(x1, x2, ws);
    nc_norm_finalize<<<64, 256, 0, stream>>>(ws);
    nc_corr_t<0><<<512, 256, 0, stream>>>(x1, x2, ws, out, dbg);  // the real kernel
    // ---- ablation probes (write only to dbg; replay-safe) ----
    nc_corr_t<1><<<512, 256, 0, stream>>>(x1, x2, ws, out, dbg);  // no epilogue
    nc_corr_t<2><<<512, 256, 0, stream>>>(x1, x2, ws, out, dbg);  // no staging
    nc_corr_t<3><<<512, 256, 0, stream>>>(x1, x2, ws, out, dbg);  // no MFMA
}

// Round 6
// 72.625 us; speedup vs baseline: 10.0448x; 10.0448x over previous
//
#include <hip/hip_runtime.h>
#include <hip/hip_bf16.h>

#define BATCH 32
#define WW 900
#define CCH 256
#define PVAL 450
#define KHALF 128     // K columns per block (K-split x2)
#define MSTRIP 128    // M rows per block
#define NCHUNK 32     // B rows staged per chunk
#define NCHUNKS 29    // 29*32 = 928 >= 900

typedef __bf16 bf16x8 __attribute__((ext_vector_type(8)));
typedef __bf16 bf16x4 __attribute__((ext_vector_type(4)));
typedef float f32x4 __attribute__((ext_vector_type(4)));

// ---------------- norm pass 1: partial sums of squares ----------------
__global__ void nc_norm_partial(const float* __restrict__ x1,
                                const float* __restrict__ x2,
                                float* __restrict__ sums) {
    int blk = blockIdx.x;
    int seg = blk & 3;
    int b = (blk >> 2) & 31;
    int which = blk >> 7;
    const float* x = which ? x2 : x1;
    int c = threadIdx.x;
    const float* p = x + ((size_t)b * WW + seg * 225) * CCH + c;
    float s = 0.f;
    #pragma unroll 8
    for (int w = 0; w < 225; ++w) {
        float v = p[(size_t)w * CCH];
        s = fmaf(v, v, s);
    }
    sums[(((which << 5) | b) * 4 + seg) * CCH + c] = s;
}

// ---------------- norm pass 2 ----------------
__global__ void nc_norm_finalize(float* __restrict__ ws) {
    int i = blockIdx.x * 256 + threadIdx.x;
    int c = i & 255;
    int wb = i >> 8;
    const float* s = ws + (size_t)wb * 4 * CCH + c;
    float t = (s[0] + s[CCH]) + (s[2 * CCH] + s[3 * CCH]);
    ws[65536 + i] = rsqrtf(fmaxf(t, 1e-12f));
}

// ---------------- main: GEMM + atomic-free diagonal reduction ----------------
// grid = 512: b = blockIdx&31, strip = (blockIdx>>5)&7, kh = blockIdx>>8.
// A (128x128) staged once in LDS; B chunks (32x128) double-buffered, coalesced loads.
// Epilogue: per-wave bijective scatter (mu=4fq+r, delta_rel) -> row-sum -> ownership fold.
__global__ __launch_bounds__(256, 2)
void nc_corr(const float* __restrict__ x1,
             const float* __restrict__ x2,
             const float* __restrict__ ws,
             float* __restrict__ out) {
    __shared__ __bf16 Abuf[MSTRIP * KHALF];       // 32 KB
    __shared__ __bf16 Bbuf[2][NCHUNK * KHALF];    // 2 x 8 KB
    __shared__ float scratch[4][16][65];          // 16.25 KB  (bank = (mu+dr)&31 -> 2-way, free)
    __shared__ float diag[2][4][64];              // 2 KB (double-buffered: no extra barrier)
    __shared__ float partial[WW];                 // 3.6 KB

    const int tid = threadIdx.x;
    const int b = blockIdx.x & 31;
    const int strip = (blockIdx.x >> 5) & 7;
    const int kh = blockIdx.x >> 8;
    const int m0 = strip * MSTRIP;
    const int k0 = kh * KHALF;

    const float* __restrict__ inv1 = ws + 65536 + b * CCH + k0;
    const float* __restrict__ inv2 = ws + 65536 + (BATCH + b) * CCH + k0;
    const float* __restrict__ x1b = x1 + (size_t)b * WW * CCH + k0;
    const float* __restrict__ x2b = x2 + (size_t)b * WW * CCH + k0;

    for (int i = tid; i < WW; i += 256) partial[i] = 0.f;
    for (int i = tid; i < 4 * 16 * 65; i += 256) ((float*)scratch)[i] = 0.f;

    const int lane = tid & 63;
    const int wave = tid >> 6;     // m-slice: rows m0 + wave*32 .. +31
    const int fr = lane & 15;
    const int fq = lane >> 4;

    // coalesced staging coords: thread = (sr, sg): row base sr, float4 col sg*4
    const int sr = tid >> 5;       // 0..7
    const int sg = tid & 31;       // 0..31  (32 x float4 = full 128-col row)

    // ---- Stage A once: 128 rows x 128 cols, coalesced, normalized, swizzled ----
    {
        float4 iv1 = *(const float4*)(inv1 + sg * 4);
        #pragma unroll
        for (int k = 0; k < 16; ++k) {
            const int row = sr + 8 * k;        // 0..127
            const int m = m0 + row;
            float4 f = make_float4(0.f, 0.f, 0.f, 0.f);
            if (m < WW) f = *(const float4*)(x1b + (size_t)m * CCH + sg * 4);
            bf16x4 v = { (__bf16)(f.x * iv1.x), (__bf16)(f.y * iv1.y),
                         (__bf16)(f.z * iv1.z), (__bf16)(f.w * iv1.w) };
            *(bf16x4*)(&Abuf[row * KHALF + (((sg >> 1) ^ (row & 7)) << 3) + (sg & 1) * 4]) = v;
        }
    }

    // ---- B staging: coalesced, 4 float4 per thread per chunk ----
    const float4 ivB = *(const float4*)(inv2 + sg * 4);
    float4 st[4];

    auto loadB = [&](int chunk) {
        #pragma unroll
        for (int k = 0; k < 4; ++k) {
            const int row = chunk * NCHUNK + sr + 8 * k;
            st[k] = (row < WW) ? *(const float4*)(x2b + (size_t)row * CCH + sg * 4)
                               : make_float4(0.f, 0.f, 0.f, 0.f);
        }
    };
    auto writeB = [&](int buf) {
        #pragma unroll
        for (int k = 0; k < 4; ++k) {
            const int row = sr + 8 * k;        // 0..31
            float4 f = st[k];
            bf16x4 v = { (__bf16)(f.x * ivB.x), (__bf16)(f.y * ivB.y),
                         (__bf16)(f.z * ivB.z), (__bf16)(f.w * ivB.w) };
            *(bf16x4*)(&Bbuf[buf][row * KHALF + (((sg >> 1) ^ (row & 7)) << 3) + (sg & 1) * 4]) = v;
        }
    };

    loadB(0);
    writeB(0);
    __syncthreads();   // A staged, B chunk0 staged, partial+scratch zeroed

    int cur = 0;
    for (int chunk = 0; chunk < NCHUNKS; ++chunk) {
        if (chunk + 1 < NCHUNKS) loadB(chunk + 1);   // issue early (T14)

        f32x4 acc[2][2];
        #pragma unroll
        for (int mt = 0; mt < 2; ++mt)
            #pragma unroll
            for (int nt = 0; nt < 2; ++nt)
                acc[mt][nt] = (f32x4){0.f, 0.f, 0.f, 0.f};

        #pragma unroll
        for (int kk = 0; kk < 4; ++kk) {
            bf16x8 afm[2], bfr[2];
            #pragma unroll
            for (int mt = 0; mt < 2; ++mt) {
                const int row = wave * 32 + mt * 16 + fr;
                const int g = (kk * 4 + fq) ^ (row & 7);
                afm[mt] = *(const bf16x8*)(&Abuf[row * KHALF + g * 8]);
            }
            #pragma unroll
            for (int nt = 0; nt < 2; ++nt) {
                const int row = nt * 16 + fr;
                const int g = (kk * 4 + fq) ^ (row & 7);
                bfr[nt] = *(const bf16x8*)(&Bbuf[cur][row * KHALF + g * 8]);
            }
            #pragma unroll
            for (int mt = 0; mt < 2; ++mt)
                #pragma unroll
                for (int nt = 0; nt < 2; ++nt)
                    acc[mt][nt] = __builtin_amdgcn_mfma_f32_16x16x32_bf16(
                        afm[mt], bfr[nt], acc[mt][nt], 0, 0, 0);
        }

        // ---- epilogue: combine equal tile-diagonals, bijective scatter ----
        // slot (dd, r): value for delta_rel = 16*dd + (4fq + r) - fr + 15, mu = 4fq + r.
        // (delta_rel, mu) <-> (dd, fq, fr, r) is a bijection -> plain writes, no collisions.
        {
            f32x4 c0 = acc[0][1];                    // dd = 0  (mt - nt = -1)
            f32x4 c1 = acc[0][0] + acc[1][1];        // dd = 1
            f32x4 c2 = acc[1][0];                    // dd = 2
            const int mub = 4 * fq;
            #pragma unroll
            for (int r = 0; r < 4; ++r) {
                const int mu = mub + r;
                const int dr = mu - fr + 15;         // 0..30
                scratch[wave][mu][dr]      = c0[r];
                scratch[wave][mu][dr + 16] = c1[r];
                scratch[wave][mu][dr + 32] = c2[r];
            }
        }

        // ---- per-wave row-sum: lane owns diagonal delta_rel = lane ----
        {
            float s = 0.f;
            #pragma unroll
            for (int m = 0; m < 16; ++m) s += scratch[wave][m][lane];
            diag[chunk & 1][wave][lane] = s;
        }

        if (chunk + 1 < NCHUNKS) writeB(cur ^ 1);
        __syncthreads();

        // ---- ownership fold: t = 32w + delta_rel, j unique per t -> no atomics ----
        if (tid < 159) {
            float s = 0.f;
            #pragma unroll
            for (int w = 0; w < 4; ++w) {
                const int dr = tid - 32 * w;
                if (dr >= 0 && dr < 63) s += diag[chunk & 1][w][dr];
            }
            int v = m0 - 32 * chunk + tid + 1319;    // in [423, 2373]
            if (v >= 1800) v -= 900;
            if (v >= 900) v -= 900;
            partial[v] += s;
        }
        cur ^= 1;
    }

    __syncthreads();
    for (int i = tid; i < WW; i += 256)
        unsafeAtomicAdd(&out[(size_t)b * WW + i], partial[i]);  // 16 blocks per batch
}

extern "C" void kernel_launch(void* const* d_in, const int* in_sizes, int n_in,
                              void* d_out, int out_size, void* d_ws, size_t ws_size,
                              hipStream_t stream) {
    const float* x1 = (const float*)d_in[0];
    const float* x2 = (const float*)d_in[1];
    float* out = (float*)d_out;
    float* ws = (float*)d_ws;   // 320 KB used: sums [0,64K) floats, inv [64K,80K) floats

    hipMemsetAsync(d_out, 0, (size_t)out_size * sizeof(float), stream);
    nc_norm_partial<<<256, 256, 0, stream>>>(x1, x2, ws);
    nc_norm_finalize<<<64, 256, 0, stream>>>(ws);
    nc_corr<<<512, 256, 0, stream>>>(x1, x2, ws, out);
}